// Round 7
// baseline (72.360 us; speedup 1.0000x reference)
//
#include <hip/hip_runtime.h>

typedef float f32x4 __attribute__((ext_vector_type(4)));

// ---------- cross-lane helpers (compile-time patterns) ----------
template<int CTRL>
__device__ __forceinline__ float dpp1(float x) {
    // DPP move with old = 1.0f (multiplicative identity), bound_ctrl=false:
    // invalid-source lanes (shift past row edge) receive 1.0f.
    return __int_as_float(__builtin_amdgcn_update_dpp(
        0x3f800000, __float_as_int(x), CTRL, 0xF, 0xF, false));
}
template<int PAT>
__device__ __forceinline__ float swz(float x) {
    return __int_as_float(__builtin_amdgcn_ds_swizzle(__float_as_int(x), PAT));
}
// xor-butterfly all-reduce within each 16-lane group
#define BFLY16(v) do { \
    v += swz<0x041F>(v); \
    v += swz<0x081F>(v); \
    v += swz<0x101F>(v); \
    v += swz<0x201F>(v); } while (0)

__device__ __forceinline__ void ntst4(float* p, float x, float y, float z, float w) {
    f32x4 v = {x, y, z, w};
    __builtin_nontemporal_store(v, (f32x4*)p);
}

// Kernel 1: segment bounds of the sorted ray_id array.
__global__ __launch_bounds__(256) void seg_bounds_kernel(
    const int* __restrict__ ray_id, int n,
    int* __restrict__ seg_start, int* __restrict__ seg_end)
{
    int i = blockIdx.x * blockDim.x + threadIdx.x;
    if (i >= n) return;
    int rid = ray_id[i];
    if (i == 0 || ray_id[i - 1] != rid) seg_start[rid] = i;
    if (i == n - 1 || ray_id[i + 1] != rid) seg_end[rid] = i + 1;
}

// Kernel 2: 16 lanes per ray, 4 samples per lane (aligned float4 tiles),
// 4 rays per wave. Single pass: scan + segment sums. NO sps broadcast here.
__global__ __launch_bounds__(256) void ray_kernel(
    const float* __restrict__ alpha,
    const float* __restrict__ values3d,
    const float* __restrict__ values1d,
    const float* __restrict__ weights,
    const float* __restrict__ sample_values,
    const int*   __restrict__ seg_start,
    const int*   __restrict__ seg_end,
    float* __restrict__ out_T,    // [N]
    float* __restrict__ out_bg,   // [R]
    float* __restrict__ out_i3,   // [R,3]
    float* __restrict__ out_i1,   // [R]
    float* __restrict__ out_spr,  // [R,3]
    int R)
{
    const int lane = threadIdx.x & 63;
    const int wid  = threadIdx.x >> 6;
    const int j    = lane & 15;              // lane within 16-lane group
    const int g    = lane >> 4;              // group (ray slot) 0..3
    const int r    = (blockIdx.x * 4 + wid) * 4 + g;
    const bool ray_ok = (r < R);
    const int rc = ray_ok ? r : 0;

    int s0 = seg_start[rc];
    int s1 = seg_end[rc];
    if (!ray_ok) { s0 = 0; s1 = 0; }

    float c = 1.0f;                          // running product carry
    float i3x = 0.f, i3y = 0.f, i3z = 0.f, i1 = 0.f;
    float sx = 0.f, sy = 0.f, sz = 0.f;

    const int base0 = s0 & ~3;               // align tile grid to float4

    for (int base = base0; base < s1; base += 64) {
        const int a = base + 4 * j;          // this lane's aligned 4-sample slot
        const bool tile_ok = (a < s1);
        const int  al = tile_ok ? a : base0; // clamp to valid in-segment addr

        // ---- issue loads at iteration top ----
        const f32x4 av  = *(const f32x4*)(alpha + al);
        const f32x4 wv  = *(const f32x4*)(weights + al);
        const f32x4 v1v = *(const f32x4*)(values1d + al);
        const f32x4 b0  = *(const f32x4*)(values3d + 3 * al);
        const f32x4 b1  = *(const f32x4*)(values3d + 3 * al + 4);
        const f32x4 b2  = *(const f32x4*)(values3d + 3 * al + 8);
        const f32x4 q0  = *(const f32x4*)(sample_values + 3 * al);
        const f32x4 q1  = *(const f32x4*)(sample_values + 3 * al + 4);
        const f32x4 q2  = *(const f32x4*)(sample_values + 3 * al + 8);

        // element ownership masks
        const bool w0 = tile_ok & (a + 0 >= s0);
        const bool w1 = tile_ok & (a + 1 >= s0) & (a + 1 < s1);
        const bool w2 = tile_ok & (a + 2 >= s0) & (a + 2 < s1);
        const bool w3 = tile_ok & (a + 3 < s1);

        float o0 = fminf(fmaxf(1.0f - av.x, 1e-7f), 1.0f); if (!w0) o0 = 1.0f;
        float o1 = fminf(fmaxf(1.0f - av.y, 1e-7f), 1.0f); if (!w1) o1 = 1.0f;
        float o2 = fminf(fmaxf(1.0f - av.z, 1e-7f), 1.0f); if (!w2) o2 = 1.0f;
        float o3 = fminf(fmaxf(1.0f - av.w, 1e-7f), 1.0f); if (!w3) o3 = 1.0f;

        const float p01  = o0 * o1;
        const float p012 = p01 * o2;
        float p = p012 * o3;                 // lane-local product

        // inclusive multiplicative scan across the 16-lane row (DPP)
        p *= dpp1<0x111>(p);                 // row_shr:1
        p *= dpp1<0x112>(p);                 // row_shr:2
        p *= dpp1<0x114>(p);                 // row_shr:4
        p *= dpp1<0x118>(p);                 // row_shr:8
        const float gincl = p;
        const float gexcl = dpp1<0x111>(gincl);  // lane j=0 gets 1.0

        const float cg = c * gexcl;
        const float t0 = cg;
        const float t1 = cg * o0;
        const float t2 = cg * p01;
        const float t3 = cg * p012;

        // accumulate (masked)
        const float W0 = w0 ? wv.x : 0.f;
        const float W1 = w1 ? wv.y : 0.f;
        const float W2 = w2 ? wv.z : 0.f;
        const float W3 = w3 ? wv.w : 0.f;
        const float M0 = w0 ? 1.f : 0.f;
        const float M1 = w1 ? 1.f : 0.f;
        const float M2 = w2 ? 1.f : 0.f;
        const float M3 = w3 ? 1.f : 0.f;

        i1  += v1v.x * W0 + v1v.y * W1 + v1v.z * W2 + v1v.w * W3;
        i3x += b0.x * W0 + b0.w * W1 + b1.z * W2 + b2.y * W3;
        i3y += b0.y * W0 + b1.x * W1 + b1.w * W2 + b2.z * W3;
        i3z += b0.z * W0 + b1.y * W1 + b2.x * W2 + b2.w * W3;
        sx  += q0.x * M0 + q0.w * M1 + q1.z * M2 + q2.y * M3;
        sy  += q0.y * M0 + q1.x * M1 + q1.w * M2 + q2.z * M3;
        sz  += q0.z * M0 + q1.y * M1 + q2.x * M2 + q2.w * M3;

        // T stores: NT only on the dense full-tile path (full cache lines)
        if (w0 & w1 & w2 & w3) {
            ntst4(out_T + a, t0, t1, t2, t3);
        } else {
            if (w0) out_T[a + 0] = t0;
            if (w1) out_T[a + 1] = t1;
            if (w2) out_T[a + 2] = t2;
            if (w3) out_T[a + 3] = t3;
        }

        // carry: chunk total lives in lane 15 of the group
        c *= swz<0x1F0>(gincl);              // bcast group-lane-15
    }

    // 7-value all-reduce within each 16-lane group
    BFLY16(i3x); BFLY16(i3y); BFLY16(i3z); BFLY16(i1);
    BFLY16(sx);  BFLY16(sy);  BFLY16(sz);

    // per-ray outputs: plain stores (spr is re-read by broadcast kernel — keep in L2)
    if (ray_ok && j == 0) {
        out_bg[r] = c;
        out_i3[3 * r + 0] = i3x;
        out_i3[3 * r + 1] = i3y;
        out_i3[3 * r + 2] = i3z;
        out_i1[r] = i1;
        out_spr[3 * r + 0] = sx;
        out_spr[3 * r + 1] = sy;
        out_spr[3 * r + 2] = sz;
    }
}

// Kernel 3: dense sample-parallel broadcast: sps[i] = spr[rid[i]].
// rid int4 loads; spr gathers are L1/L2 hits (1.5 MB, mostly-same-ray);
// NT dwordx4 stores (48B/lane contiguous, never re-read).
__global__ __launch_bounds__(256) void sps_kernel(
    const int* __restrict__ ray_id,
    const float* __restrict__ spr,
    float* __restrict__ out_sps,
    int nquad)  // N/4
{
    int t = blockIdx.x * blockDim.x + threadIdx.x;
    if (t >= nquad) return;
    const int a = t * 4;
    const int4 rv = *(const int4*)(ray_id + a);

    const float x0 = spr[3 * rv.x + 0], y0 = spr[3 * rv.x + 1], z0 = spr[3 * rv.x + 2];
    const float x1 = spr[3 * rv.y + 0], y1 = spr[3 * rv.y + 1], z1 = spr[3 * rv.y + 2];
    const float x2 = spr[3 * rv.z + 0], y2 = spr[3 * rv.z + 1], z2 = spr[3 * rv.z + 2];
    const float x3 = spr[3 * rv.w + 0], y3 = spr[3 * rv.w + 1], z3 = spr[3 * rv.w + 2];

    ntst4(out_sps + 3 * a,     x0, y0, z0, x1);
    ntst4(out_sps + 3 * a + 4, y1, z1, x2, y2);
    ntst4(out_sps + 3 * a + 8, z2, x3, y3, z3);
}

extern "C" void kernel_launch(void* const* d_in, const int* in_sizes, int n_in,
                              void* d_out, int out_size, void* d_ws, size_t ws_size,
                              hipStream_t stream) {
    const float* alpha = (const float*)d_in[0];
    const float* v3    = (const float*)d_in[1];
    const float* v1    = (const float*)d_in[2];
    const float* w     = (const float*)d_in[3];
    const float* sv    = (const float*)d_in[4];
    const int*   rid   = (const int*)d_in[5];

    int N = in_sizes[0];
    int R = (out_size - 4 * N) / 8;  // out = N + R + 3R + R + 3R + 3N

    int* seg_start = (int*)d_ws;
    int* seg_end   = seg_start + R;
    (void)hipMemsetAsync(d_ws, 0, (size_t)2 * R * sizeof(int), stream);

    float* out     = (float*)d_out;
    float* out_T   = out;
    float* out_bg  = out + N;
    float* out_i3  = out_bg + R;
    float* out_i1  = out_i3 + 3 * (size_t)R;
    float* out_spr = out_i1 + R;
    float* out_sps = out_spr + 3 * (size_t)R;

    seg_bounds_kernel<<<(N + 255) / 256, 256, 0, stream>>>(rid, N, seg_start, seg_end);

    // 4 waves/block, 4 rays/wave -> 16 rays per block
    int blocks = (R + 15) / 16;
    ray_kernel<<<blocks, 256, 0, stream>>>(alpha, v3, v1, w, sv, seg_start, seg_end,
                                           out_T, out_bg, out_i3, out_i1, out_spr, R);

    int nquad = N / 4;
    sps_kernel<<<(nquad + 255) / 256, 256, 0, stream>>>(rid, out_spr, out_sps, nquad);
}

// Round 8
// 55.762 us; speedup vs baseline: 1.2977x; 1.2977x over previous
//
#include <hip/hip_runtime.h>

typedef float f32x4 __attribute__((ext_vector_type(4)));

// ---------- cross-lane helpers (compile-time patterns) ----------
template<int CTRL>
__device__ __forceinline__ float dpp1(float x) {
    // DPP move, old = 1.0f (multiplicative identity), bound_ctrl=false.
    return __int_as_float(__builtin_amdgcn_update_dpp(
        0x3f800000, __float_as_int(x), CTRL, 0xF, 0xF, false));
}
template<int CTRL>
__device__ __forceinline__ float dpp0(float x) {
    // DPP move, additive identity: bound_ctrl=true -> out-of-row reads 0.
    return __int_as_float(__builtin_amdgcn_update_dpp(
        0, __float_as_int(x), CTRL, 0xF, 0xF, true));
}
template<int PAT>
__device__ __forceinline__ float swz(float x) {
    return __int_as_float(__builtin_amdgcn_ds_swizzle(__float_as_int(x), PAT));
}
// funnel sum of 16-lane row into lane 15 (VALU DPP pipe)
#define FUNNEL16(v) do { \
    v += dpp0<0x111>(v); \
    v += dpp0<0x112>(v); \
    v += dpp0<0x114>(v); \
    v += dpp0<0x118>(v); } while (0)
// xor-butterfly all-reduce within each 16-lane group (all lanes get total)
#define BFLY16(v) do { \
    v += swz<0x041F>(v); \
    v += swz<0x081F>(v); \
    v += swz<0x101F>(v); \
    v += swz<0x201F>(v); } while (0)

__device__ __forceinline__ void ntst4(float* p, float x, float y, float z, float w) {
    f32x4 v = {x, y, z, w};
    __builtin_nontemporal_store(v, (f32x4*)p);
}

// Kernel 1: segment bounds, packed adjacently: se[2*rid]=start, se[2*rid+1]=end.
__global__ __launch_bounds__(256) void seg_bounds_kernel(
    const int* __restrict__ ray_id, int n, int* __restrict__ seg_se)
{
    int i = blockIdx.x * blockDim.x + threadIdx.x;
    if (i >= n) return;
    int rid = ray_id[i];
    if (i == 0 || ray_id[i - 1] != rid) seg_se[2 * rid + 0] = i;
    if (i == n - 1 || ray_id[i + 1] != rid) seg_se[2 * rid + 1] = i + 1;
}

// Kernel 2: 16 lanes per ray, 4 samples per lane, 4 rays/wave. Fused:
// scan + segment sums + sps broadcast (pass 2 hides in latency shadow).
__global__ __launch_bounds__(256) void ray_kernel(
    const float* __restrict__ alpha,
    const float* __restrict__ values3d,
    const float* __restrict__ values1d,
    const float* __restrict__ weights,
    const float* __restrict__ sample_values,
    const int*   __restrict__ seg_se,
    float* __restrict__ out_T,    // [N]
    float* __restrict__ out_bg,   // [R]
    float* __restrict__ out_i3,   // [R,3]
    float* __restrict__ out_i1,   // [R]
    float* __restrict__ out_spr,  // [R,3]
    float* __restrict__ out_sps,  // [N,3]
    int R)
{
    const int lane = threadIdx.x & 63;
    const int wid  = threadIdx.x >> 6;
    const int j    = lane & 15;              // lane within 16-lane group
    const int g    = lane >> 4;              // group (ray slot) 0..3
    const int r    = (blockIdx.x * 4 + wid) * 4 + g;
    const bool ray_ok = (r < R);
    const int rc = ray_ok ? r : 0;

    const int2 se = ((const int2*)seg_se)[rc];   // one 8B load
    int s0 = se.x, s1 = se.y;
    if (!ray_ok) { s0 = 0; s1 = 0; }

    float c = 1.0f;                          // running product carry
    float i3x = 0.f, i3y = 0.f, i3z = 0.f, i1 = 0.f;
    float sx = 0.f, sy = 0.f, sz = 0.f;

    const int base0 = s0 & ~3;               // align tile grid to float4

    for (int base = base0; base < s1; base += 64) {
        const int a = base + 4 * j;          // this lane's aligned 4-sample slot
        const bool tile_ok = (a < s1);
        const int  al = tile_ok ? a : base0; // clamp to valid in-segment addr

        // ---- issue loads at iteration top ----
        const f32x4 av  = *(const f32x4*)(alpha + al);
        const f32x4 wv  = *(const f32x4*)(weights + al);
        const f32x4 v1v = *(const f32x4*)(values1d + al);
        const f32x4 b0  = *(const f32x4*)(values3d + 3 * al);
        const f32x4 b1  = *(const f32x4*)(values3d + 3 * al + 4);
        const f32x4 b2  = *(const f32x4*)(values3d + 3 * al + 8);
        const f32x4 q0  = *(const f32x4*)(sample_values + 3 * al);
        const f32x4 q1  = *(const f32x4*)(sample_values + 3 * al + 4);
        const f32x4 q2  = *(const f32x4*)(sample_values + 3 * al + 8);

        // element ownership masks
        const bool w0 = tile_ok & (a + 0 >= s0);
        const bool w1 = tile_ok & (a + 1 >= s0) & (a + 1 < s1);
        const bool w2 = tile_ok & (a + 2 >= s0) & (a + 2 < s1);
        const bool w3 = tile_ok & (a + 3 < s1);

        float o0 = fminf(fmaxf(1.0f - av.x, 1e-7f), 1.0f); if (!w0) o0 = 1.0f;
        float o1 = fminf(fmaxf(1.0f - av.y, 1e-7f), 1.0f); if (!w1) o1 = 1.0f;
        float o2 = fminf(fmaxf(1.0f - av.z, 1e-7f), 1.0f); if (!w2) o2 = 1.0f;
        float o3 = fminf(fmaxf(1.0f - av.w, 1e-7f), 1.0f); if (!w3) o3 = 1.0f;

        const float p01  = o0 * o1;
        const float p012 = p01 * o2;
        float p = p012 * o3;                 // lane-local product

        // inclusive multiplicative scan across the 16-lane row (DPP)
        p *= dpp1<0x111>(p);                 // row_shr:1
        p *= dpp1<0x112>(p);                 // row_shr:2
        p *= dpp1<0x114>(p);                 // row_shr:4
        p *= dpp1<0x118>(p);                 // row_shr:8
        const float gincl = p;
        const float gexcl = dpp1<0x111>(gincl);  // lane j=0 gets 1.0

        const float cg = c * gexcl;
        const float t0 = cg;
        const float t1 = cg * o0;
        const float t2 = cg * p01;
        const float t3 = cg * p012;

        // accumulate (masked)
        const float W0 = w0 ? wv.x : 0.f;
        const float W1 = w1 ? wv.y : 0.f;
        const float W2 = w2 ? wv.z : 0.f;
        const float W3 = w3 ? wv.w : 0.f;
        const float M0 = w0 ? 1.f : 0.f;
        const float M1 = w1 ? 1.f : 0.f;
        const float M2 = w2 ? 1.f : 0.f;
        const float M3 = w3 ? 1.f : 0.f;

        i1  += v1v.x * W0 + v1v.y * W1 + v1v.z * W2 + v1v.w * W3;
        i3x += b0.x * W0 + b0.w * W1 + b1.z * W2 + b2.y * W3;
        i3y += b0.y * W0 + b1.x * W1 + b1.w * W2 + b2.z * W3;
        i3z += b0.z * W0 + b1.y * W1 + b2.x * W2 + b2.w * W3;
        sx  += q0.x * M0 + q0.w * M1 + q1.z * M2 + q2.y * M3;
        sy  += q0.y * M0 + q1.x * M1 + q1.w * M2 + q2.z * M3;
        sz  += q0.z * M0 + q1.y * M1 + q2.x * M2 + q2.w * M3;

        // T stores: NT only on dense full-tile path (full cache lines)
        if (w0 & w1 & w2 & w3) {
            ntst4(out_T + a, t0, t1, t2, t3);
        } else {
            if (w0) out_T[a + 0] = t0;
            if (w1) out_T[a + 1] = t1;
            if (w2) out_T[a + 2] = t2;
            if (w3) out_T[a + 3] = t3;
        }

        // carry: chunk total lives in lane 15 of the group
        c *= swz<0x1F0>(gincl);              // bcast group-lane-15
    }

    // i3*/i1: funnel into lane 15 via DPP (VALU pipe, short chain)
    FUNNEL16(i3x); FUNNEL16(i3y); FUNNEL16(i3z); FUNNEL16(i1);
    // sx/sy/sz: all lanes need the total for pass 2
    BFLY16(sx);  BFLY16(sy);  BFLY16(sz);

    if (ray_ok && j == 15) {
        out_bg[r] = c;
        out_i3[3 * r + 0] = i3x;
        out_i3[3 * r + 1] = i3y;
        out_i3[3 * r + 2] = i3z;
        out_i1[r] = i1;
        out_spr[3 * r + 0] = sx;
        out_spr[3 * r + 1] = sy;
        out_spr[3 * r + 2] = sz;
    }

    // pass 2: broadcast sum_per_ray over the segment (free: latency shadow)
    for (int base = base0; base < s1; base += 64) {
        const int a = base + 4 * j;
        const bool tile_ok = (a < s1);
        const bool w0 = tile_ok & (a + 0 >= s0);
        const bool w1 = tile_ok & (a + 1 >= s0) & (a + 1 < s1);
        const bool w2 = tile_ok & (a + 2 >= s0) & (a + 2 < s1);
        const bool w3 = tile_ok & (a + 3 < s1);
        if (w0 & w1 & w2 & w3) {
            ntst4(out_sps + 3 * a,     sx, sy, sz, sx);
            ntst4(out_sps + 3 * a + 4, sy, sz, sx, sy);
            ntst4(out_sps + 3 * a + 8, sz, sx, sy, sz);
        } else {
            if (w0) { out_sps[3*a+0] = sx; out_sps[3*a+1]  = sy; out_sps[3*a+2]  = sz; }
            if (w1) { out_sps[3*a+3] = sx; out_sps[3*a+4]  = sy; out_sps[3*a+5]  = sz; }
            if (w2) { out_sps[3*a+6] = sx; out_sps[3*a+7]  = sy; out_sps[3*a+8]  = sz; }
            if (w3) { out_sps[3*a+9] = sx; out_sps[3*a+10] = sy; out_sps[3*a+11] = sz; }
        }
    }
}

extern "C" void kernel_launch(void* const* d_in, const int* in_sizes, int n_in,
                              void* d_out, int out_size, void* d_ws, size_t ws_size,
                              hipStream_t stream) {
    const float* alpha = (const float*)d_in[0];
    const float* v3    = (const float*)d_in[1];
    const float* v1    = (const float*)d_in[2];
    const float* w     = (const float*)d_in[3];
    const float* sv    = (const float*)d_in[4];
    const int*   rid   = (const int*)d_in[5];

    int N = in_sizes[0];
    int R = (out_size - 4 * N) / 8;  // out = N + R + 3R + R + 3R + 3N

    int* seg_se = (int*)d_ws;        // [R][2] packed (start, end)
    (void)hipMemsetAsync(d_ws, 0, (size_t)2 * R * sizeof(int), stream);

    float* out     = (float*)d_out;
    float* out_T   = out;
    float* out_bg  = out + N;
    float* out_i3  = out_bg + R;
    float* out_i1  = out_i3 + 3 * (size_t)R;
    float* out_spr = out_i1 + R;
    float* out_sps = out_spr + 3 * (size_t)R;

    seg_bounds_kernel<<<(N + 255) / 256, 256, 0, stream>>>(rid, N, seg_se);

    // 4 waves/block, 4 rays/wave -> 16 rays per block
    int blocks = (R + 15) / 16;
    ray_kernel<<<blocks, 256, 0, stream>>>(alpha, v3, v1, w, sv, seg_se,
                                           out_T, out_bg, out_i3, out_i1, out_spr,
                                           out_sps, R);
}